// Round 8
// baseline (217.551 us; speedup 1.0000x reference)
//
#include <hip/hip_runtime.h>
#include <hip/hip_cooperative_groups.h>
#include <math.h>

namespace cg = cooperative_groups;

#define B_ 8
#define BIGF 3.4e38f

// ws layout: minarr : B_*N uint rowmin + B_*M uint colmin (uint-ordered d^2).
//
// R8: ONE cooperative dispatch (init -> minsq -> reduce with grid syncs).
// Evidence: gaps ~2.7us per node boundary (calibrated from R2's measured
// minsq=41.36 inside total=98.0); R0-R6 inner-loop attacks all neutral or
// worse -> loop is at the m07-calibrated issue wall; R7's slice-combine
// reduce regressed 16us (dependent strided-load chain) -> atomicMin combine
// restored. This round keeps the PROVEN R0/R6 minsq body bit-identical and
// only collapses the node structure: memset+memset+minsq+reduce -> 1
// cooperative node (5 boundaries -> 2). Grid 1024 blocks x 256 thr at
// __launch_bounds__(256,4) = exactly 4 blocks/CU x 256 CU co-resident.
// G16 guard: phase-2 reads minarr via __hip_atomic_load(AGENT) (sc0) so
// per-CU L1 can't serve stale phase-0 init lines. Fallback: if
// hipLaunchCooperativeKernel errors, run the R6 3-node path (neutral).

template <int QPT, int CHUNK>
__device__ __forceinline__ void minsq_body(
    const float* __restrict__ tar, const float* __restrict__ src,
    unsigned int* __restrict__ minarr, int N, int M,
    int bx, int by, int bz)
{
    const int dir = (bz >= B_) ? 1 : 0;
    const int b   = dir ? (bz - B_) : bz;
    const float* __restrict__ qry = dir ? src : tar;   // raw float3 streams
    const float* __restrict__ pts = dir ? tar : src;
    const int K = dir ? M : N;   // query count
    const int L = dir ? N : M;   // reference count
    unsigned int* __restrict__ out =
        minarr + (dir ? (size_t)B_ * N : (size_t)0) + (size_t)b * K;

    const int base = by * CHUNK;
    if (base >= L) return;                      // block-uniform; syncs are
    const int cnt = min(CHUNK, L - base);       // outside this function

    // Stage refs as float4 {x,y,z,|p|^2} (bitwise-identical fma form).
    __shared__ float4 sp[CHUNK];
    const float* __restrict__ p3 = pts + ((size_t)b * L + base) * 3;
    const int t = threadIdx.x;
    for (int i = t; i < cnt; i += 256) {
        float x = p3[3 * i], y = p3[3 * i + 1], zc = p3[3 * i + 2];
        sp[i] = make_float4(x, y, zc, fmaf(x, x, fmaf(y, y, zc * zc)));
    }
    __syncthreads();

    const float* __restrict__ q3 = qry + (size_t)b * K * 3;
    const int qbase = bx * (256 * QPT);
    float qx2[QPT], qy2[QPT], qz2[QPT], qw[QPT], mn[QPT];
#pragma unroll
    for (int k = 0; k < QPT; ++k) {
        int qi = qbase + k * 256 + t;
        if (qi < K) {
            float x = q3[3 * qi], y = q3[3 * qi + 1], zc = q3[3 * qi + 2];
            qx2[k] = -2.f * x; qy2[k] = -2.f * y; qz2[k] = -2.f * zc;
            qw[k] = fmaf(x, x, fmaf(y, y, zc * zc));
        } else {
            qx2[k] = 0.f; qy2[k] = 0.f; qz2[k] = 0.f; qw[k] = 0.f;
        }
        mn[k] = BIGF;
    }

    if (cnt == CHUNK) {
#pragma unroll 4
        for (int j = 0; j < CHUNK; j += 2) {
            float4 p0 = sp[j];
            float4 p1 = sp[j + 1];
#pragma unroll
            for (int k = 0; k < QPT; ++k) {
                float d0 = fmaf(qx2[k], p0.x, fmaf(qy2[k], p0.y,
                           fmaf(qz2[k], p0.z, p0.w)));
                float d1 = fmaf(qx2[k], p1.x, fmaf(qy2[k], p1.y,
                           fmaf(qz2[k], p1.z, p1.w)));
                mn[k] = fminf(mn[k], fminf(d0, d1));   // v_min3_f32
            }
        }
    } else {
        int j = 0;
        for (; j + 1 < cnt; j += 2) {
            float4 p0 = sp[j];
            float4 p1 = sp[j + 1];
#pragma unroll
            for (int k = 0; k < QPT; ++k) {
                float d0 = fmaf(qx2[k], p0.x, fmaf(qy2[k], p0.y,
                           fmaf(qz2[k], p0.z, p0.w)));
                float d1 = fmaf(qx2[k], p1.x, fmaf(qy2[k], p1.y,
                           fmaf(qz2[k], p1.z, p1.w)));
                mn[k] = fminf(mn[k], fminf(d0, d1));
            }
        }
        if (j < cnt) {
            float4 p0 = sp[j];
#pragma unroll
            for (int k = 0; k < QPT; ++k) {
                float d0 = fmaf(qx2[k], p0.x, fmaf(qy2[k], p0.y,
                           fmaf(qz2[k], p0.z, p0.w)));
                mn[k] = fminf(mn[k], d0);
            }
        }
    }

#pragma unroll
    for (int k = 0; k < QPT; ++k) {
        int qi = qbase + k * 256 + t;
        if (qi < K) {
            float d2 = fmaxf(mn[k] + qw[k], 0.f);  // clamp roundoff negatives
            atomicMin(&out[qi], __float_as_uint(d2));
        }
    }
}

// Stripe-sum sqrt of both regions over `nblocks` participating blocks,
// 3 scaled atomicAdds into outp (pre-zeroed). AGENT-scope loads bypass L1
// (needed in the fused kernel where phase-0 init lines may sit in L1).
__device__ __forceinline__ void reduce_body(
    unsigned int* __restrict__ minarr, float* __restrict__ outp,
    int N, int M, int linb, int nblocks)
{
    const int nt = B_ * N, ns = B_ * M;
    const int gid = linb * 256 + threadIdx.x;
    const int stride = nblocks * 256;
    float s_t = 0.f, s_s = 0.f;
    for (int i = gid; i < nt; i += stride) {
        unsigned int u = __hip_atomic_load(&minarr[i], __ATOMIC_RELAXED,
                                           __HIP_MEMORY_SCOPE_AGENT);
        s_t += sqrtf(__uint_as_float(u));
    }
    for (int i = gid; i < ns; i += stride) {
        unsigned int u = __hip_atomic_load(&minarr[nt + i], __ATOMIC_RELAXED,
                                           __HIP_MEMORY_SCOPE_AGENT);
        s_s += sqrtf(__uint_as_float(u));
    }
#pragma unroll
    for (int off = 32; off > 0; off >>= 1) {
        s_t += __shfl_down(s_t, off);
        s_s += __shfl_down(s_s, off);
    }
    __shared__ float rt[4], rs[4];
    const int wid = threadIdx.x >> 6, lid = threadIdx.x & 63;
    if (lid == 0) { rt[wid] = s_t; rs[wid] = s_s; }
    __syncthreads();
    if (threadIdx.x == 0) {
        float ct = (rt[0] + rt[1] + rt[2] + rt[3]) / (float)nt;  // complete
        float ac = (rs[0] + rs[1] + rs[2] + rs[3]) / (float)ns;  // accuracy
        atomicAdd(&outp[0], ac);
        atomicAdd(&outp[1], ct);
        atomicAdd(&outp[2], 0.5f * (ac + ct));
    }
}

// ---- fused cooperative kernel: init -> sync -> minsq -> sync -> reduce ----
template <int QPT, int CHUNK>
__global__ __launch_bounds__(256, 4) void fused_kernel(
    const float* __restrict__ tar, const float* __restrict__ src,
    unsigned int* __restrict__ minarr, float* __restrict__ outp, int N, int M)
{
    const int linb = ((int)blockIdx.z * gridDim.y + blockIdx.y) * gridDim.x
                     + blockIdx.x;
    const int gtid = linb * 256 + (int)threadIdx.x;

    // phase 0: init minarr to +inf bits; zero outp.
    const int tot = B_ * (N + M);
    if (gtid < tot) minarr[gtid] = 0x7F800000u;
    if (gtid < 3) outp[gtid] = 0.f;

    cg::this_grid().sync();

    // phase 1: proven minsq body (bit-identical math to R0/R6).
    minsq_body<QPT, CHUNK>(tar, src, minarr, N, M,
                           blockIdx.x, blockIdx.y, blockIdx.z);

    cg::this_grid().sync();

    // phase 2: 32 blocks reduce+finalize (others exit; no more syncs).
    if (linb < 32) reduce_body(minarr, outp, N, M, linb, 32);
}

// ---- fallback standalone kernels (R6 path) ----
template <int QPT, int CHUNK>
__global__ __launch_bounds__(256, 4) void minsq_kernel(
    const float* __restrict__ tar, const float* __restrict__ src,
    unsigned int* __restrict__ minarr, int N, int M)
{
    minsq_body<QPT, CHUNK>(tar, src, minarr, N, M,
                           blockIdx.x, blockIdx.y, blockIdx.z);
}

__global__ __launch_bounds__(256) void reduce_kernel(
    unsigned int* __restrict__ minarr, float* __restrict__ outp, int N, int M)
{
    reduce_body(minarr, outp, N, M, blockIdx.x, gridDim.x);
}

extern "C" void kernel_launch(void* const* d_in, const int* in_sizes, int n_in,
                              void* d_out, int out_size, void* d_ws, size_t ws_size,
                              hipStream_t stream) {
    const float* tar = (const float*)d_in[0];
    const float* src = (const float*)d_in[1];
    const int N = in_sizes[0] / (B_ * 3);
    const int M = in_sizes[1] / (B_ * 3);

    unsigned int* minarr = (unsigned int*)d_ws;
    float* outp = (float*)d_out;

    constexpr int QPT = 8, CHUNK = 128;
    const int KL = (N > M) ? N : M;
    const int gx = (KL + 256 * QPT - 1) / (256 * QPT);   // 2
    const int gy = (KL + CHUNK - 1) / CHUNK;             // 32
    dim3 grid(gx, gy, 2 * B_);                            // 1024 blocks
    dim3 block(256);

    void* args[] = {(void*)&tar, (void*)&src, (void*)&minarr,
                    (void*)&outp, (void*)&N, (void*)&M};
    hipError_t err = hipLaunchCooperativeKernel(
        (const void*)&fused_kernel<QPT, CHUNK>, grid, block, args, 0, stream);

    if (err != hipSuccess) {
        // Fallback: R6 3-node path (memset init + minsq + reduce).
        (void)hipGetLastError();  // clear sticky error
        hipMemsetAsync(minarr, 0xFF,
                       (size_t)B_ * (N + M) * sizeof(unsigned int), stream);
        hipMemsetAsync(outp, 0, 3 * sizeof(float), stream);
        minsq_kernel<QPT, CHUNK><<<grid, block, 0, stream>>>(
            tar, src, minarr, N, M);
        reduce_kernel<<<dim3(32), block, 0, stream>>>(minarr, outp, N, M);
    }
}